// Round 3
// baseline (1897.366 us; speedup 1.0000x reference)
//
#include <hip/hip_runtime.h>
#include <hip/hip_bf16.h>

#define V_ 50000
#define E_ 100
#define H_ 128
#define B_ 16
#define S_ 4096

typedef unsigned short u16;
typedef unsigned int   u32;

__device__ __forceinline__ float bf2f(u16 x) {
  return __uint_as_float(((u32)x) << 16);
}
__device__ __forceinline__ u16 f2bf(float x) {
  __hip_bfloat16 b = __float2bfloat16(x);
  return *reinterpret_cast<u16*>(&b);
}
__device__ __forceinline__ float sigm(float x) { return 1.0f / (1.0f + __expf(-x)); }
__device__ __forceinline__ float tanh_f(float x) {
  float e = __expf(2.0f * x);
  return 1.0f - 2.0f / (e + 1.0f);
}

// ---------------------------------------------------------------------------
// Transpose W_x (f32, [512][100] row-major; o = g*128+h) into k-major
// interleaved layout: Wt[(k/4)*512*4 + o*4 + (k%4)] (f32) so the xg kernel
// does one coalesced float4 load per 4-k chunk per output.
// ---------------------------------------------------------------------------
__global__ void prep_wt(const float* __restrict__ Wx, float* __restrict__ Wt) {
  int i = blockIdx.x * 256 + threadIdx.x;        // over 512*100
  if (i < 512 * E_) {
    int o = i / E_, k = i % E_;
    Wt[((size_t)(k >> 2) * 512 + o) * 4 + (k & 3)] = Wx[i];
  }
}

// ---------------------------------------------------------------------------
// Pack U_l, U_r (f32 [5][128][128] = [g][h][k]) into k-major bf16 pairs:
// Up[k*640 + g*128 + h] = (bf16(Ur) << 16) | bf16(Ul)
// Lane hh then loads Up[k*640 + g*128 + hh]: 4 B/lane, fully coalesced,
// one load feeds both the U_l and U_r FMA for gate g at depth k.
// ---------------------------------------------------------------------------
__global__ void prep_u(const float* __restrict__ Ul, const float* __restrict__ Ur,
                       u32* __restrict__ Up) {
  int i = blockIdx.x * 256 + threadIdx.x;        // i = (g*128+h)*128 + k
  if (i < 5 * H_ * H_) {
    int k  = i & 127;
    int gh = i >> 7;
    Up[(size_t)k * 640 + gh] = (u32)f2bf(Ul[i]) | ((u32)f2bf(Ur[i]) << 16);
  }
}

// bsum = b_l + b_r (only the sum is ever used)
__global__ void prep_bsum(const float* __restrict__ bl, const float* __restrict__ br,
                          float* __restrict__ bs) {
  int i = blockIdx.x * 256 + threadIdx.x;
  if (i < 5 * H_) bs[i] = bl[i] + br[i];
}

// ---------------------------------------------------------------------------
// xg[row][o] = dot(emb[seq[row]], W_x[o]) + b_x[o]; stored bf16.
// ---------------------------------------------------------------------------
#define XGR 32
__global__ __launch_bounds__(512) void xg_kernel(
    const float* __restrict__ emb, const float* __restrict__ Wt,
    const float* __restrict__ bx, const int* __restrict__ seq,
    u16* __restrict__ xg)
{
  const int o = threadIdx.x;
  const int row0 = blockIdx.x * XGR;

  int tb[XGR];
  #pragma unroll
  for (int r = 0; r < XGR; ++r)
    tb[r] = __builtin_amdgcn_readfirstlane(seq[row0 + r]) * E_;

  float acc[XGR];
  #pragma unroll
  for (int r = 0; r < XGR; ++r) acc[r] = 0.0f;

  for (int k0 = 0; k0 < E_; k0 += 4) {
    float4 wv = *reinterpret_cast<const float4*>(Wt + ((size_t)(k0 >> 2) * 512 + o) * 4);
    #pragma unroll
    for (int r = 0; r < XGR; ++r) {
      float e0 = emb[tb[r] + k0];
      float e1 = emb[tb[r] + k0 + 1];
      float e2 = emb[tb[r] + k0 + 2];
      float e3 = emb[tb[r] + k0 + 3];
      acc[r] += e0 * wv.x + e1 * wv.y + e2 * wv.z + e3 * wv.w;
    }
  }
  float bxv = bx[o];
  #pragma unroll
  for (int r = 0; r < XGR; ++r) {
    ((__hip_bfloat16*)xg)[(size_t)(row0 + r) * 512 + o] = __float2bfloat16(acc[r] + bxv);
  }
}

// ---------------------------------------------------------------------------
// Level 0: c = sig(i)*tanh(u), h = sig(o)*tanh(c). Gates i(xg0),o(xg2),u(xg3).
// ---------------------------------------------------------------------------
__global__ __launch_bounds__(256) void level0_kernel(
    const u16* __restrict__ xg, const float* __restrict__ bs,
    float* __restrict__ h0, float* __restrict__ c0)
{
  int t = blockIdx.x * 256 + threadIdx.x;        // over B*S*H
  int hh = t & (H_ - 1);
  size_t row = (size_t)(t >> 7);
  const u16* xr = xg + row * 512;
  float pi = bf2f(xr[hh])          + bs[hh];
  float po = bf2f(xr[2 * H_ + hh]) + bs[3 * H_ + hh];
  float pu = bf2f(xr[3 * H_ + hh]) + bs[4 * H_ + hh];
  float c = sigm(pi) * tanh_f(pu);
  float h = sigm(po) * tanh_f(c);
  h0[t] = h;
  c0[t] = c;
}

// ---------------------------------------------------------------------------
// Levels 1..12. Block = 128 threads (one per h), ND nodes per block.
// U via coalesced k-major bf16-pair loads (reused across ND nodes);
// h_l/h_r block-uniform -> scalar loads (parallel to VALU).
// ---------------------------------------------------------------------------
template<int ND>
__global__ __launch_bounds__(128) void level_kernel(
    const u16* __restrict__ xg,
    const u32* __restrict__ Up, const float* __restrict__ bs,
    const int* __restrict__ deprow,
    const float* __restrict__ hPrev, const float* __restrict__ cPrev,
    float* __restrict__ hOut, float* __restrict__ cOut, int n)
{
  const int hh = threadIdx.x;
  const int b  = blockIdx.y;
  const int j0 = blockIdx.x * ND;

  float bsv[5];
  #pragma unroll
  for (int g = 0; g < 5; ++g) bsv[g] = bs[g * H_ + hh];

  float acc[ND][5];
  #pragma unroll
  for (int u = 0; u < ND; ++u) {
    int dj = __builtin_amdgcn_readfirstlane(deprow[j0 + u]);
    const u16* xr = xg + ((size_t)b * S_ + dj) * 512;
    float x0 = bf2f(xr[hh]);
    float x1 = bf2f(xr[H_ + hh]);
    float x2 = bf2f(xr[2 * H_ + hh]);
    float x3 = bf2f(xr[3 * H_ + hh]);
    acc[u][0] = x0 + bsv[0];   // i   <- xg gate 0
    acc[u][1] = x1 + bsv[1];   // f_l <- xg gate 1
    acc[u][2] = x1 + bsv[2];   // f_r <- xg gate 1
    acc[u][3] = x2 + bsv[3];   // o   <- xg gate 2
    acc[u][4] = x3 + bsv[4];   // u   <- xg gate 3
  }

  const float* hb = hPrev + ((size_t)b * 2 * n + 2 * j0) * H_;
  const u32* uprow = Up + hh;

  #pragma unroll 4
  for (int k = 0; k < H_; ++k) {
    u32 w[5];
    #pragma unroll
    for (int g = 0; g < 5; ++g) w[g] = uprow[(size_t)k * 640 + g * 128];
    float ul[5], ur[5];
    #pragma unroll
    for (int g = 0; g < 5; ++g) {
      ul[g] = __uint_as_float(w[g] << 16);
      ur[g] = __uint_as_float(w[g] & 0xffff0000u);
    }
    #pragma unroll
    for (int u = 0; u < ND; ++u) {
      float hl = hb[(size_t)(2 * u) * H_ + k];       // uniform -> s_load
      float hr = hb[(size_t)(2 * u + 1) * H_ + k];   // uniform -> s_load
      #pragma unroll
      for (int g = 0; g < 5; ++g)
        acc[u][g] += ul[g] * hl + ur[g] * hr;
    }
  }

  #pragma unroll
  for (int u = 0; u < ND; ++u) {
    float iv = sigm(acc[u][0]);
    float fl = sigm(acc[u][1]);
    float fr = sigm(acc[u][2]);
    float ov = sigm(acc[u][3]);
    float uv = tanh_f(acc[u][4]);
    size_t pidx = ((size_t)b * 2 * n + 2 * (j0 + u)) * H_ + hh;
    float cl = cPrev[pidx];
    float cr = cPrev[pidx + H_];
    float c = iv * uv + fl * cl + fr * cr;
    float h = ov * tanh_f(c);
    size_t oidx = ((size_t)b * n + (j0 + u)) * H_ + hh;
    hOut[oidx] = h;
    cOut[oidx] = c;
  }
}

// ---------------------------------------------------------------------------
// Final: out = concat(h[:,0].flatten(), c[:,0].flatten()) as f32 (2048 + 2048)
// ---------------------------------------------------------------------------
__global__ void out_kernel(const float* __restrict__ hF, const float* __restrict__ cF,
                           float* __restrict__ out) {
  int i = blockIdx.x * 256 + threadIdx.x;
  if (i < B_ * H_)            out[i] = hF[i];
  else if (i < 2 * B_ * H_)   out[i] = cF[i - B_ * H_];
}

extern "C" void kernel_launch(void* const* d_in, const int* in_sizes, int n_in,
                              void* d_out, int out_size, void* d_ws, size_t ws_size,
                              hipStream_t stream)
{
  const float* emb = (const float*)d_in[0];
  const float* Wx  = (const float*)d_in[1];
  const float* bx  = (const float*)d_in[2];
  const float* Ul  = (const float*)d_in[3];
  const float* bl  = (const float*)d_in[4];
  const float* Ur  = (const float*)d_in[5];
  const float* br  = (const float*)d_in[6];
  const int* seq = (const int*)d_in[7];
  const int* dep = (const int*)d_in[8];

  char* p = (char*)d_ws;
  float* Wt = (float*)p;  p += (size_t)512 * E_ * 4;            // 204,800
  u32* Up = (u32*)p;      p += (size_t)H_ * 640 * 4;            // 327,680
  float* bs = (float*)p;  p += (size_t)5 * H_ * 4;              // 2,560
  p = (char*)d_ws + (1 << 20);                                  // align to 1 MB
  u16* xg = (u16*)p;      p += (size_t)B_ * S_ * 512 * 2;       // 67,108,864 (bf16)
  float* hA = (float*)p;  p += (size_t)B_ * S_ * H_ * 4;        // 33,554,432
  float* cA = (float*)p;  p += (size_t)B_ * S_ * H_ * 4;
  float* hB = (float*)p;  p += (size_t)B_ * (S_ / 2) * H_ * 4;  // 16,777,216
  float* cB = (float*)p;  p += (size_t)B_ * (S_ / 2) * H_ * 4;

  prep_wt<<<dim3((512 * E_ + 255) / 256), dim3(256), 0, stream>>>(Wx, Wt);
  prep_u<<<dim3((5 * H_ * H_ + 255) / 256), dim3(256), 0, stream>>>(Ul, Ur, (u32*)Up);
  prep_bsum<<<dim3(3), dim3(256), 0, stream>>>(bl, br, bs);
  xg_kernel<<<dim3(B_ * S_ / XGR), dim3(512), 0, stream>>>(emb, Wt, bx, seq, xg);
  level0_kernel<<<dim3(B_ * S_ * H_ / 256), dim3(256), 0, stream>>>(xg, bs, hA, cA);

  float *hp = hA, *cp = cA, *ho = hB, *co = cB;
  for (int l = 1; l < 13; ++l) {
    int n = S_ >> l;
    const int* deprow = dep + (size_t)(l - 1) * (S_ / 2);
    int nd = n < 16 ? n : 16;
    dim3 grid(n / nd, B_);
    switch (nd) {
      case 16: level_kernel<16><<<grid, 128, 0, stream>>>(xg, Up, bs, deprow, hp, cp, ho, co, n); break;
      case 8:  level_kernel<8><<<grid, 128, 0, stream>>>(xg, Up, bs, deprow, hp, cp, ho, co, n); break;
      case 4:  level_kernel<4><<<grid, 128, 0, stream>>>(xg, Up, bs, deprow, hp, cp, ho, co, n); break;
      case 2:  level_kernel<2><<<grid, 128, 0, stream>>>(xg, Up, bs, deprow, hp, cp, ho, co, n); break;
      case 1:  level_kernel<1><<<grid, 128, 0, stream>>>(xg, Up, bs, deprow, hp, cp, ho, co, n); break;
    }
    float* t;
    t = hp; hp = ho; ho = t;
    t = cp; cp = co; co = t;
  }

  out_kernel<<<dim3(16), dim3(256), 0, stream>>>(hp, cp, (float*)d_out);
}

// Round 4
// 481.842 us; speedup vs baseline: 3.9377x; 3.9377x over previous
//
#include <hip/hip_runtime.h>
#include <hip/hip_bf16.h>

#define V_ 50000
#define E_ 100
#define H_ 128
#define B_ 16
#define S_ 4096

typedef unsigned short u16;
typedef unsigned int   u32;
typedef short bf16x8 __attribute__((ext_vector_type(8)));  // 8 bf16 = 4 VGPRs
typedef float f32x4  __attribute__((ext_vector_type(4)));

__device__ __forceinline__ float bf2f(u16 x) {
  return __uint_as_float(((u32)x) << 16);
}
__device__ __forceinline__ u16 f2bf(float x) {
  __hip_bfloat16 b = __float2bfloat16(x);
  return *reinterpret_cast<u16*>(&b);
}
__device__ __forceinline__ float sigm(float x) { return 1.0f / (1.0f + __expf(-x)); }
__device__ __forceinline__ float tanh_f(float x) {
  float e = __expf(2.0f * x);
  return 1.0f - 2.0f / (e + 1.0f);
}

// ---------------------------------------------------------------------------
// Prep: emb (f32 [V][100]) -> embB (bf16 [V][128], k-padded with 0)
// ---------------------------------------------------------------------------
__global__ void prep_emb(const float* __restrict__ emb, u16* __restrict__ embB) {
  int i = blockIdx.x * 256 + threadIdx.x;          // over V*128
  if (i < V_ * 128) {
    int k = i & 127, t = i >> 7;
    embB[i] = (k < E_) ? f2bf(emb[t * E_ + k]) : (u16)0;
  }
}

// ---------------------------------------------------------------------------
// Prep: W_x (f32 [512][100], o=g*128+h) -> MFMA B-fragment order, bf16:
// Bx[((t*4+s)*64+lane)*8+j] = B[k=s*32+(lane>>4)*8+j][o=t*16+(lane&15)]
// (k >= 100 zero-padded). t in [0,32), s in [0,4).
// ---------------------------------------------------------------------------
__global__ void prep_bswx(const float* __restrict__ Wx, u16* __restrict__ Bx) {
  int i = blockIdx.x * 256 + threadIdx.x;          // over 32*4*64*8 = 65536
  if (i < 32 * 4 * 64 * 8) {
    int j = i & 7, l = (i >> 3) & 63, s = (i >> 9) & 3, t = i >> 11;
    int k = s * 32 + (l >> 4) * 8 + j;
    int o = t * 16 + (l & 15);
    Bx[i] = (k < E_) ? f2bf(Wx[o * E_ + k]) : (u16)0;
  }
}

// ---------------------------------------------------------------------------
// Prep: Ucat = [Ul; Ur] (k in [0,256)) -> B-fragment order, bf16:
// Bu[((t*8+s)*64+lane)*8+j] = Ucat[k=s*32+(lane>>4)*8+j][gh=t*16+(lane&15)]
// t in [0,40), s in [0,8). Ul/Ur are f32 [5][128][128] = [gh][k].
// ---------------------------------------------------------------------------
__global__ void prep_bswu(const float* __restrict__ Ul, const float* __restrict__ Ur,
                          u16* __restrict__ Bu) {
  int i = blockIdx.x * 256 + threadIdx.x;          // over 40*8*64*8 = 163840
  if (i < 40 * 8 * 64 * 8) {
    int j = i & 7, l = (i >> 3) & 63, s = (i >> 9) & 7, t = i >> 12;
    int k = s * 32 + (l >> 4) * 8 + j;
    int gh = t * 16 + (l & 15);
    float v = (k < 128) ? Ul[gh * 128 + k] : Ur[gh * 128 + (k - 128)];
    Bu[i] = f2bf(v);
  }
}

// bsum = b_l + b_r (only the sum is ever used)
__global__ void prep_bsum(const float* __restrict__ bl, const float* __restrict__ br,
                          float* __restrict__ bs) {
  int i = blockIdx.x * 256 + threadIdx.x;
  if (i < 5 * H_) bs[i] = bl[i] + br[i];
}

// ---------------------------------------------------------------------------
// xg GEMM via MFMA: xg[m][o] = dot(embB[seq[m]][0:128], B[0:128][o]) + bx[o]
// M = B*S = 65536 (Mtile=32), N = 512, K = 128. Block 256 thr = 4 waves;
// wave w owns col-tiles w*8..w*8+7. Output bf16.
// ---------------------------------------------------------------------------
__global__ __launch_bounds__(256) void xg_mfma(
    const u16* __restrict__ embB, const u16* __restrict__ Bx,
    const float* __restrict__ bx, const int* __restrict__ seq,
    u16* __restrict__ xg)
{
  const int w = threadIdx.x >> 6, lane = threadIdx.x & 63;
  const int quad = lane >> 4, l15 = lane & 15;
  const int m0 = blockIdx.x * 32;

  f32x4 acc[2][8];
  #pragma unroll
  for (int r = 0; r < 2; ++r)
    #pragma unroll
    for (int t = 0; t < 8; ++t) acc[r][t] = (f32x4){0.f, 0.f, 0.f, 0.f};

  int tok0 = seq[m0 + l15];
  int tok1 = seq[m0 + 16 + l15];
  const u16* a0p = embB + (size_t)tok0 * 128 + quad * 8;
  const u16* a1p = embB + (size_t)tok1 * 128 + quad * 8;

  #pragma unroll
  for (int s = 0; s < 4; ++s) {
    bf16x8 a0 = *reinterpret_cast<const bf16x8*>(a0p + s * 32);
    bf16x8 a1 = *reinterpret_cast<const bf16x8*>(a1p + s * 32);
    #pragma unroll
    for (int ti = 0; ti < 8; ++ti) {
      int t = w * 8 + ti;
      bf16x8 b = *reinterpret_cast<const bf16x8*>(Bx + ((size_t)(t * 4 + s) * 64 + lane) * 8);
      acc[0][ti] = __builtin_amdgcn_mfma_f32_16x16x32_bf16(a0, b, acc[0][ti], 0, 0, 0);
      acc[1][ti] = __builtin_amdgcn_mfma_f32_16x16x32_bf16(a1, b, acc[1][ti], 0, 0, 0);
    }
  }

  #pragma unroll
  for (int r = 0; r < 2; ++r) {
    #pragma unroll
    for (int ti = 0; ti < 8; ++ti) {
      int o = (w * 8 + ti) * 16 + l15;
      float bxo = bx[o];
      #pragma unroll
      for (int reg = 0; reg < 4; ++reg) {
        int m = m0 + r * 16 + quad * 4 + reg;     // C layout: row=quad*4+reg
        xg[(size_t)m * 512 + o] = f2bf(acc[r][ti][reg] + bxo);
      }
    }
  }
}

// ---------------------------------------------------------------------------
// Level 0: c = sig(i)*tanh(u), h = sig(o)*tanh(c). h stored bf16, c fp32.
// xg gates: 0->i, 2->o, 3->u (f gates multiply zero c).
// ---------------------------------------------------------------------------
__global__ __launch_bounds__(256) void level0_kernel(
    const u16* __restrict__ xg, const float* __restrict__ bs,
    u16* __restrict__ h0, float* __restrict__ c0)
{
  int t = blockIdx.x * 256 + threadIdx.x;        // over B*S*H
  int hh = t & (H_ - 1);
  size_t row = (size_t)(t >> 7);
  const u16* xr = xg + row * 512;
  float pi = bf2f(xr[hh])        + bs[hh];
  float po = bf2f(xr[256 + hh])  + bs[3 * H_ + hh];
  float pu = bf2f(xr[384 + hh])  + bs[4 * H_ + hh];
  float c = sigm(pi) * tanh_f(pu);
  float h = sigm(po) * tanh_f(c);
  h0[t] = f2bf(h);
  c0[t] = c;
}

// ---------------------------------------------------------------------------
// Levels 1..12 via MFMA.
// A = hPrev viewed as [M=16n][K=256] bf16 (children 2j,2j+1 are contiguous).
// B = swizzled Ucat [256][640]. Block: Mtile=32, full N=640. 4 waves; wave w
// owns col-offsets q in {2w,2w+1} of every gate -> gate combine is
// register-local. Epilogue adds xg[dep] + bsum, applies gates, writes
// h (bf16, next level's A) and c (fp32).
// ---------------------------------------------------------------------------
__global__ __launch_bounds__(256) void level_mfma(
    const u16* __restrict__ xg, const u16* __restrict__ Bu,
    const float* __restrict__ bs, const int* __restrict__ deprow,
    const u16* __restrict__ hPrev, const float* __restrict__ cPrev,
    u16* __restrict__ hOut, float* __restrict__ cOut,
    int n, int ln2n, int Mtot)
{
  const int w = threadIdx.x >> 6, lane = threadIdx.x & 63;
  const int quad = lane >> 4, l15 = lane & 15;
  const int m0 = blockIdx.x * 32;
  const bool r1ok = (m0 + 16) < Mtot;

  f32x4 acc[2][2][5];                            // [row-tile][q-offset][gate]
  #pragma unroll
  for (int r = 0; r < 2; ++r)
    #pragma unroll
    for (int qi = 0; qi < 2; ++qi)
      #pragma unroll
      for (int g = 0; g < 5; ++g) acc[r][qi][g] = (f32x4){0.f, 0.f, 0.f, 0.f};

  const u16* a0p = hPrev + (size_t)(m0 + l15) * 256 + quad * 8;
  const u16* a1p = r1ok ? (hPrev + (size_t)(m0 + 16 + l15) * 256 + quad * 8) : a0p;

  #pragma unroll
  for (int s = 0; s < 8; ++s) {
    bf16x8 a0 = *reinterpret_cast<const bf16x8*>(a0p + s * 32);
    bf16x8 a1 = *reinterpret_cast<const bf16x8*>(a1p + s * 32);
    #pragma unroll
    for (int qi = 0; qi < 2; ++qi) {
      int q = 2 * w + qi;
      #pragma unroll
      for (int g = 0; g < 5; ++g) {
        int t = g * 8 + q;
        bf16x8 b = *reinterpret_cast<const bf16x8*>(Bu + ((size_t)(t * 8 + s) * 64 + lane) * 8);
        acc[0][qi][g] = __builtin_amdgcn_mfma_f32_16x16x32_bf16(a0, b, acc[0][qi][g], 0, 0, 0);
        acc[1][qi][g] = __builtin_amdgcn_mfma_f32_16x16x32_bf16(a1, b, acc[1][qi][g], 0, 0, 0);
      }
    }
  }

  float bsv[2][5];
  #pragma unroll
  for (int qi = 0; qi < 2; ++qi)
    #pragma unroll
    for (int g = 0; g < 5; ++g)
      bsv[qi][g] = bs[g * 128 + (2 * w + qi) * 16 + l15];

  #pragma unroll
  for (int r = 0; r < 2; ++r) {
    if (r == 1 && !r1ok) break;
    #pragma unroll
    for (int reg = 0; reg < 4; ++reg) {
      int m = m0 + r * 16 + quad * 4 + reg;      // C layout: row=quad*4+reg
      int j = m & (n - 1);
      int b = m >> ln2n;
      int dj = deprow[j];
      const u16* xr = xg + ((size_t)b * S_ + dj) * 512;
      const float* cpr = cPrev + (size_t)m * 256;
      #pragma unroll
      for (int qi = 0; qi < 2; ++qi) {
        int hh = (2 * w + qi) * 16 + l15;
        float x0 = bf2f(xr[hh]);
        float x1 = bf2f(xr[128 + hh]);
        float x2 = bf2f(xr[256 + hh]);
        float x3 = bf2f(xr[384 + hh]);
        float pi  = acc[r][qi][0][reg] + x0 + bsv[qi][0];
        float pfl = acc[r][qi][1][reg] + x1 + bsv[qi][1];
        float pfr = acc[r][qi][2][reg] + x1 + bsv[qi][2];
        float po  = acc[r][qi][3][reg] + x2 + bsv[qi][3];
        float pu  = acc[r][qi][4][reg] + x3 + bsv[qi][4];
        float cl = cpr[hh];
        float cr = cpr[128 + hh];
        float c = sigm(pi) * tanh_f(pu) + sigm(pfl) * cl + sigm(pfr) * cr;
        float h = sigm(po) * tanh_f(c);
        hOut[(size_t)m * 128 + hh] = f2bf(h);
        cOut[(size_t)m * 128 + hh] = c;
      }
    }
  }
}

// ---------------------------------------------------------------------------
// Final: out = concat(h[:,0] (bf16->f32), c[:,0]) : 2048 + 2048 f32
// ---------------------------------------------------------------------------
__global__ void out_kernel(const u16* __restrict__ hF, const float* __restrict__ cF,
                           float* __restrict__ out) {
  int i = blockIdx.x * 256 + threadIdx.x;
  if (i < B_ * H_)            out[i] = bf2f(hF[i]);
  else if (i < 2 * B_ * H_)   out[i] = cF[i - B_ * H_];
}

extern "C" void kernel_launch(void* const* d_in, const int* in_sizes, int n_in,
                              void* d_out, int out_size, void* d_ws, size_t ws_size,
                              hipStream_t stream)
{
  const float* emb = (const float*)d_in[0];
  const float* Wx  = (const float*)d_in[1];
  const float* bx  = (const float*)d_in[2];
  const float* Ul  = (const float*)d_in[3];
  const float* bl  = (const float*)d_in[4];
  const float* Ur  = (const float*)d_in[5];
  const float* br  = (const float*)d_in[6];
  const int* seq = (const int*)d_in[7];
  const int* dep = (const int*)d_in[8];

  char* p = (char*)d_ws;
  u16* embB = (u16*)p;  p += (size_t)V_ * 128 * 2;               // 12,800,000
  u16* BswX = (u16*)p;  p += (size_t)32 * 4 * 64 * 8 * 2;        // 131,072
  u16* BswU = (u16*)p;  p += (size_t)40 * 8 * 64 * 8 * 2;        // 327,680
  float* bs = (float*)p;                                          // 2,560
  p = (char*)d_ws + (16u << 20);                                  // 16 MB mark
  u16* xg = (u16*)p;     p += (size_t)B_ * S_ * 512 * 2;          // 67,108,864
  u16* hA = (u16*)p;     p += (size_t)B_ * S_ * H_ * 2;           // 16,777,216
  float* cA = (float*)p; p += (size_t)B_ * S_ * H_ * 4;           // 33,554,432
  u16* hB = (u16*)p;     p += (size_t)B_ * (S_ / 2) * H_ * 2;     // 8,388,608
  float* cB = (float*)p; p += (size_t)B_ * (S_ / 2) * H_ * 4;     // 16,777,216

  prep_emb<<<dim3((V_ * 128 + 255) / 256), dim3(256), 0, stream>>>(emb, embB);
  prep_bswx<<<dim3(256), dim3(256), 0, stream>>>(Wx, BswX);
  prep_bswu<<<dim3(640), dim3(256), 0, stream>>>(Ul, Ur, BswU);
  prep_bsum<<<dim3(3), dim3(256), 0, stream>>>(bl, br, bs);

  xg_mfma<<<dim3(B_ * S_ / 32), dim3(256), 0, stream>>>(embB, BswX, bx, seq, xg);
  level0_kernel<<<dim3(B_ * S_ * H_ / 256), dim3(256), 0, stream>>>(xg, bs, hA, cA);

  u16 *hp = hA, *ho = hB;
  float *cp = cA, *co = cB;
  for (int l = 1; l < 13; ++l) {
    int n = S_ >> l;
    int Mtot = B_ * n;
    int nblocks = (Mtot + 31) / 32;
    const int* deprow = dep + (size_t)(l - 1) * (S_ / 2);
    level_mfma<<<dim3(nblocks), dim3(256), 0, stream>>>(
        xg, BswU, bs, deprow, hp, cp, ho, co, n, 12 - l, Mtot);
    u16* th = hp; hp = ho; ho = th;
    float* tc = cp; cp = co; co = tc;
  }

  out_kernel<<<dim3(16), dim3(256), 0, stream>>>(hp, cp, (float*)d_out);
}

// Round 5
// 345.239 us; speedup vs baseline: 5.4958x; 1.3957x over previous
//
#include <hip/hip_runtime.h>
#include <hip/hip_bf16.h>

#define V_ 50000
#define E_ 100
#define H_ 128
#define B_ 16
#define S_ 4096

typedef unsigned short u16;
typedef unsigned int   u32;
typedef short bf16x8 __attribute__((ext_vector_type(8)));  // 8 bf16 = 4 VGPRs
typedef float f32x4  __attribute__((ext_vector_type(4)));

__device__ __forceinline__ float bf2f(u16 x) {
  return __uint_as_float(((u32)x) << 16);
}
__device__ __forceinline__ u16 f2bf(float x) {
  __hip_bfloat16 b = __float2bfloat16(x);
  return *reinterpret_cast<u16*>(&b);
}
__device__ __forceinline__ float sigm(float x) { return 1.0f / (1.0f + __expf(-x)); }
__device__ __forceinline__ float tanh_f(float x) {
  float e = __expf(2.0f * x);
  return 1.0f - 2.0f / (e + 1.0f);
}

// ---------------------------------------------------------------------------
// Prep: emb (f32 [V][100]) -> embB (bf16 [V][128], k-padded with 0)
// ---------------------------------------------------------------------------
__global__ void prep_emb(const float* __restrict__ emb, u16* __restrict__ embB) {
  int i = blockIdx.x * 256 + threadIdx.x;          // over V*128
  if (i < V_ * 128) {
    int k = i & 127, t = i >> 7;
    embB[i] = (k < E_) ? f2bf(emb[t * E_ + k]) : (u16)0;
  }
}

// ---------------------------------------------------------------------------
// Prep: W_x (f32 [512][100], o=g*128+h) -> MFMA B-fragment order, bf16:
// Bx[((t*4+s)*64+lane)*8+j] = B[k=s*32+(lane>>4)*8+j][o=t*16+(lane&15)]
// ---------------------------------------------------------------------------
__global__ void prep_bswx(const float* __restrict__ Wx, u16* __restrict__ Bx) {
  int i = blockIdx.x * 256 + threadIdx.x;          // over 32*4*64*8 = 65536
  if (i < 32 * 4 * 64 * 8) {
    int j = i & 7, l = (i >> 3) & 63, s = (i >> 9) & 3, t = i >> 11;
    int k = s * 32 + (l >> 4) * 8 + j;
    int o = t * 16 + (l & 15);
    Bx[i] = (k < E_) ? f2bf(Wx[o * E_ + k]) : (u16)0;
  }
}

// ---------------------------------------------------------------------------
// Prep: Ucat = [Ul; Ur] (k in [0,256)) -> B-fragment order, bf16:
// Bu[((t*8+s)*64+lane)*8+j] = Ucat[k=s*32+(lane>>4)*8+j][gh=t*16+(lane&15)]
// ---------------------------------------------------------------------------
__global__ void prep_bswu(const float* __restrict__ Ul, const float* __restrict__ Ur,
                          u16* __restrict__ Bu) {
  int i = blockIdx.x * 256 + threadIdx.x;          // over 40*8*64*8 = 163840
  if (i < 40 * 8 * 64 * 8) {
    int j = i & 7, l = (i >> 3) & 63, s = (i >> 9) & 7, t = i >> 12;
    int k = s * 32 + (l >> 4) * 8 + j;
    int gh = t * 16 + (l & 15);
    float v = (k < 128) ? Ul[gh * 128 + k] : Ur[gh * 128 + (k - 128)];
    Bu[i] = f2bf(v);
  }
}

// bsum = b_l + b_r (only the sum is ever used)
__global__ void prep_bsum(const float* __restrict__ bl, const float* __restrict__ br,
                          float* __restrict__ bs) {
  int i = blockIdx.x * 256 + threadIdx.x;
  if (i < 5 * H_) bs[i] = bl[i] + br[i];
}

// ---------------------------------------------------------------------------
// xg GEMM via MFMA: xg[m][o] = dot(embB[seq[m]], B[][o]) + bx[o]; bf16 out.
// M=65536 (Mtile=32), N=512, K=128. 512 thr = 8 waves; wave w owns 4 col-tiles.
// ---------------------------------------------------------------------------
__global__ __launch_bounds__(512) void xg_mfma(
    const u16* __restrict__ embB, const u16* __restrict__ Bx,
    const float* __restrict__ bx, const int* __restrict__ seq,
    u16* __restrict__ xg)
{
  const int w = threadIdx.x >> 6, lane = threadIdx.x & 63;
  const int quad = lane >> 4, l15 = lane & 15;
  const int m0 = blockIdx.x * 32;

  f32x4 acc[2][4];
  #pragma unroll
  for (int r = 0; r < 2; ++r)
    #pragma unroll
    for (int t = 0; t < 4; ++t) acc[r][t] = (f32x4){0.f, 0.f, 0.f, 0.f};

  int tok0 = seq[m0 + l15];
  int tok1 = seq[m0 + 16 + l15];
  const u16* a0p = embB + (size_t)tok0 * 128 + quad * 8;
  const u16* a1p = embB + (size_t)tok1 * 128 + quad * 8;

  #pragma unroll
  for (int s = 0; s < 4; ++s) {
    bf16x8 a0 = *reinterpret_cast<const bf16x8*>(a0p + s * 32);
    bf16x8 a1 = *reinterpret_cast<const bf16x8*>(a1p + s * 32);
    #pragma unroll
    for (int ti = 0; ti < 4; ++ti) {
      int t = w * 4 + ti;
      bf16x8 b = *reinterpret_cast<const bf16x8*>(Bx + ((size_t)(t * 4 + s) * 64 + lane) * 8);
      acc[0][ti] = __builtin_amdgcn_mfma_f32_16x16x32_bf16(a0, b, acc[0][ti], 0, 0, 0);
      acc[1][ti] = __builtin_amdgcn_mfma_f32_16x16x32_bf16(a1, b, acc[1][ti], 0, 0, 0);
    }
  }

  #pragma unroll
  for (int r = 0; r < 2; ++r) {
    #pragma unroll
    for (int ti = 0; ti < 4; ++ti) {
      int o = (w * 4 + ti) * 16 + l15;
      float bxo = bx[o];
      #pragma unroll
      for (int reg = 0; reg < 4; ++reg) {
        int m = m0 + r * 16 + quad * 4 + reg;     // C layout: row=quad*4+reg
        xg[(size_t)m * 512 + o] = f2bf(acc[r][ti][reg] + bxo);
      }
    }
  }
}

// ---------------------------------------------------------------------------
// Level 0: c = sig(i)*tanh(u), h = sig(o)*tanh(c). h bf16, c fp32.
// ---------------------------------------------------------------------------
__global__ __launch_bounds__(256) void level0_kernel(
    const u16* __restrict__ xg, const float* __restrict__ bs,
    u16* __restrict__ h0, float* __restrict__ c0)
{
  int t = blockIdx.x * 256 + threadIdx.x;        // over B*S*H
  int hh = t & (H_ - 1);
  size_t row = (size_t)(t >> 7);
  const u16* xr = xg + row * 512;
  float pi = bf2f(xr[hh])        + bs[hh];
  float po = bf2f(xr[256 + hh])  + bs[3 * H_ + hh];
  float pu = bf2f(xr[384 + hh])  + bs[4 * H_ + hh];
  float c = sigm(pi) * tanh_f(pu);
  float h = sigm(po) * tanh_f(c);
  h0[t] = f2bf(h);
  c0[t] = c;
}

// ---------------------------------------------------------------------------
// Gather ALL levels' xg[b][dep[j]] rows into dense per-level slices, in
// gate-interleaved layout: xgath[rid][hh] = ushort4{g0,g1,g2,g3}.
// Row-id -> level via clz: level-l slice starts at off_l = 65536 - (65536>>(l-1)).
// ---------------------------------------------------------------------------
#define RTOT 65520
__global__ __launch_bounds__(256) void gather_xg(
    const u16* __restrict__ xg, const int* __restrict__ dep,
    u16* __restrict__ xgath)
{
  int rid = blockIdx.x * 2 + (threadIdx.x >> 7);
  int hh = threadIdx.x & 127;
  if (rid >= RTOT) return;
  u32 x = 65536u - (u32)rid;                 // (16, 65536]
  int l = __clz((int)(x - 1)) - 15;          // level in [1,12]
  int m = rid - 65536 + (65536 >> (l - 1));  // row within level
  int n = S_ >> l;
  int b = m >> (12 - l);
  int j = m & (n - 1);
  int dj = dep[(l - 1) * (S_ / 2) + j];
  const u16* src = xg + ((size_t)b * S_ + dj) * 512;
  ushort4 v;
  v.x = src[hh]; v.y = src[128 + hh]; v.z = src[256 + hh]; v.w = src[384 + hh];
  reinterpret_cast<ushort4*>(xgath)[(size_t)rid * 128 + hh] = v;
}

// ---------------------------------------------------------------------------
// Levels 1..12 via MFMA. A = hPrev [M][256] bf16; B = swizzled Ucat [256][640].
// 512 thr = 8 waves; wave w owns col-offset q=w of EVERY gate -> gate combine
// register-local; acc = 2x5 f32x4 = 40 VGPRs. Epilogue: one ushort4 from the
// pre-gathered xgl + 2 c-floats per output.
// ---------------------------------------------------------------------------
__global__ __launch_bounds__(512) void level_mfma(
    const ushort4* __restrict__ xgl, const u16* __restrict__ Bu,
    const float* __restrict__ bs,
    const u16* __restrict__ hPrev, const float* __restrict__ cPrev,
    u16* __restrict__ hOut, float* __restrict__ cOut, int Mtot)
{
  const int w = threadIdx.x >> 6, lane = threadIdx.x & 63;
  const int quad = lane >> 4, l15 = lane & 15;
  const int hh = w * 16 + l15;
  const int m0 = blockIdx.x * 32;
  const bool r1ok = (m0 + 16) < Mtot;

  f32x4 acc[2][5];
  #pragma unroll
  for (int r = 0; r < 2; ++r)
    #pragma unroll
    for (int g = 0; g < 5; ++g) acc[r][g] = (f32x4){0.f, 0.f, 0.f, 0.f};

  const u16* a0p = hPrev + (size_t)(m0 + l15) * 256 + quad * 8;
  const u16* a1p = r1ok ? (a0p + 16 * 256) : a0p;

  #pragma unroll
  for (int s = 0; s < 8; ++s) {
    bf16x8 a0 = *reinterpret_cast<const bf16x8*>(a0p + s * 32);
    bf16x8 a1 = *reinterpret_cast<const bf16x8*>(a1p + s * 32);
    #pragma unroll
    for (int g = 0; g < 5; ++g) {
      int t = g * 8 + w;
      bf16x8 b = *reinterpret_cast<const bf16x8*>(Bu + ((size_t)(t * 8 + s) * 64 + lane) * 8);
      acc[0][g] = __builtin_amdgcn_mfma_f32_16x16x32_bf16(a0, b, acc[0][g], 0, 0, 0);
      acc[1][g] = __builtin_amdgcn_mfma_f32_16x16x32_bf16(a1, b, acc[1][g], 0, 0, 0);
    }
  }

  float bsv[5];
  #pragma unroll
  for (int g = 0; g < 5; ++g) bsv[g] = bs[g * 128 + hh];

  #pragma unroll
  for (int r = 0; r < 2; ++r) {
    if (r == 1 && !r1ok) break;
    #pragma unroll
    for (int reg = 0; reg < 4; ++reg) {
      int m = m0 + r * 16 + quad * 4 + reg;      // C layout: row=quad*4+reg
      ushort4 v = xgl[(size_t)m * 128 + hh];
      float x0 = bf2f(v.x), x1 = bf2f(v.y), x2 = bf2f(v.z), x3 = bf2f(v.w);
      float pi  = acc[r][0][reg] + x0 + bsv[0];
      float pfl = acc[r][1][reg] + x1 + bsv[1];
      float pfr = acc[r][2][reg] + x1 + bsv[2];
      float po  = acc[r][3][reg] + x2 + bsv[3];
      float pu  = acc[r][4][reg] + x3 + bsv[4];
      float cl = cPrev[(size_t)m * 256 + hh];
      float cr = cPrev[(size_t)m * 256 + 128 + hh];
      float c = sigm(pi) * tanh_f(pu) + sigm(pfl) * cl + sigm(pfr) * cr;
      float h = sigm(po) * tanh_f(c);
      hOut[(size_t)m * 128 + hh] = f2bf(h);
      cOut[(size_t)m * 128 + hh] = c;
    }
  }
}

// ---------------------------------------------------------------------------
// Final: out = concat(h[:,0] (bf16->f32), c[:,0]) : 2048 + 2048 f32
// ---------------------------------------------------------------------------
__global__ void out_kernel(const u16* __restrict__ hF, const float* __restrict__ cF,
                           float* __restrict__ out) {
  int i = blockIdx.x * 256 + threadIdx.x;
  if (i < B_ * H_)            out[i] = bf2f(hF[i]);
  else if (i < 2 * B_ * H_)   out[i] = cF[i - B_ * H_];
}

extern "C" void kernel_launch(void* const* d_in, const int* in_sizes, int n_in,
                              void* d_out, int out_size, void* d_ws, size_t ws_size,
                              hipStream_t stream)
{
  const float* emb = (const float*)d_in[0];
  const float* Wx  = (const float*)d_in[1];
  const float* bx  = (const float*)d_in[2];
  const float* Ul  = (const float*)d_in[3];
  const float* bl  = (const float*)d_in[4];
  const float* Ur  = (const float*)d_in[5];
  const float* br  = (const float*)d_in[6];
  const int* seq = (const int*)d_in[7];
  const int* dep = (const int*)d_in[8];

  char* base = (char*)d_ws;
  // Region 0 (67.1 MB): embB lives here during xg_mfma; reused as xgath after
  // (gather_xg runs strictly after xg_mfma on the stream).
  u16* embB  = (u16*)base;                                        // 12,800,000 B
  u16* xgath = (u16*)base;                                        // 67,092,480 B
  char* p = base + (size_t)RTOT * 1024;                           // 67,092,480
  u16* BswX = (u16*)p;   p += 131072;
  u16* BswU = (u16*)p;   p += 327680;
  float* bs = (float*)p; p += 4096;
  u16* xg = (u16*)p;     p += (size_t)B_ * S_ * 512 * 2;          // 67,108,864
  u16* hA = (u16*)p;     p += (size_t)B_ * S_ * H_ * 2;           // 16,777,216
  float* cA = (float*)p; p += (size_t)B_ * S_ * H_ * 4;           // 33,554,432
  u16* hB = (u16*)p;     p += (size_t)B_ * (S_ / 2) * H_ * 2;     // 8,388,608
  float* cB = (float*)p; p += (size_t)B_ * (S_ / 2) * H_ * 4;     // 16,777,216

  prep_emb<<<dim3((V_ * 128 + 255) / 256), dim3(256), 0, stream>>>(emb, embB);
  prep_bswx<<<dim3(256), dim3(256), 0, stream>>>(Wx, BswX);
  prep_bswu<<<dim3(640), dim3(256), 0, stream>>>(Ul, Ur, BswU);
  prep_bsum<<<dim3(3), dim3(256), 0, stream>>>(bl, br, bs);

  xg_mfma<<<dim3(B_ * S_ / 32), dim3(512), 0, stream>>>(embB, BswX, bx, seq, xg);
  level0_kernel<<<dim3(B_ * S_ * H_ / 256), dim3(256), 0, stream>>>(xg, bs, hA, cA);
  gather_xg<<<dim3((RTOT + 1) / 2), dim3(256), 0, stream>>>(xg, dep, xgath);

  u16 *hp = hA, *ho = hB;
  float *cp = cA, *co = cB;
  size_t off = 0;                                   // level slice offset (rows)
  for (int l = 1; l < 13; ++l) {
    int n = S_ >> l;
    int Mtot = B_ * n;
    int nblocks = (Mtot + 31) / 32;
    level_mfma<<<dim3(nblocks), dim3(512), 0, stream>>>(
        (const ushort4*)(xgath + off * 512), BswU, bs, hp, cp, ho, co, Mtot);
    off += Mtot;
    u16* th = hp; hp = ho; ho = th;
    float* tc = cp; cp = co; co = tc;
  }

  out_kernel<<<dim3(16), dim3(256), 0, stream>>>(hp, cp, (float*)d_out);
}